// Round 8
// baseline (472.936 us; speedup 1.0000x reference)
//
#include <hip/hip_runtime.h>

#define NB 4
#define NS 1024
#define ND 1024
#define NH 16
#define NDH 64

typedef __attribute__((ext_vector_type(8))) short short8;
typedef __attribute__((ext_vector_type(4))) short s16x4;
typedef __attribute__((ext_vector_type(4))) float f32x4;

// bf16-finite masked-score sentinel (0xFF7F0000); see round-1 analysis.
#define SENT (-3.3895313892515355e38f)

static __device__ __forceinline__ unsigned short f2bf(float f) {
    unsigned u = __builtin_bit_cast(unsigned, f);
    u += 0x7fffu + ((u >> 16) & 1u);          // RNE
    return (unsigned short)(u >> 16);
}

static __device__ __forceinline__ f32x4 mfma16(short8 a, short8 b, f32x4 c) {
    return __builtin_amdgcn_mfma_f32_16x16x32_bf16(a, b, c, 0, 0, 0);
}

typedef const __attribute__((address_space(1))) unsigned int gu32_t;
typedef __attribute__((address_space(3))) unsigned int su32_t;
#define GLOAD_LDS16(gp, lp) \
    __builtin_amdgcn_global_load_lds((gu32_t*)(const void*)(gp), (su32_t*)(void*)(lp), 16, 0, 0)

// ---------------------------------------------------------------- cast f32->bf16
__global__ __launch_bounds__(256) void cast_to_bf16(
    const float* __restrict__ x,  const float* __restrict__ wq,
    const float* __restrict__ wk, const float* __restrict__ wv,
    const float* __restrict__ wo, short* __restrict__ xb,
    short* __restrict__ wqb, short* __restrict__ wkb,
    short* __restrict__ wvb, short* __restrict__ wob)
{
    int i = blockIdx.x * 256 + threadIdx.x;     // float4 index; total 2M
    const float* s; short* d; int off;
    const int XQ = 1 << 20, WQ = 1 << 18;
    if (i < XQ)               { s = x;  d = xb;  off = i; }
    else if (i < XQ + WQ)     { s = wq; d = wqb; off = i - XQ; }
    else if (i < XQ + 2 * WQ) { s = wk; d = wkb; off = i - XQ - WQ; }
    else if (i < XQ + 3 * WQ) { s = wv; d = wvb; off = i - XQ - 2 * WQ; }
    else                      { s = wo; d = wob; off = i - XQ - 3 * WQ; }
    float4 v = ((const float4*)s)[off];
    s16x4 r = { (short)f2bf(v.x), (short)f2bf(v.y), (short)f2bf(v.z), (short)f2bf(v.w) };
    ((s16x4*)d)[off] = r;
}

// ---------------------------------------------------------------- merged QKV GEMM
// z=0: Q (bias bq, scaled) -> [B,H,S,DH]; z=1: K (scaled) -> [B,H,S,DH];
// z=2: V (bias bv) -> TRANSPOSED [B,H,DH,S].
__global__ __launch_bounds__(256) void gemm_qkv(
    const short* __restrict__ X, const short* __restrict__ Wq,
    const short* __restrict__ Wk, const short* __restrict__ Wv,
    const float* __restrict__ bq, const float* __restrict__ bv,
    short* __restrict__ qd, short* __restrict__ kd, short* __restrict__ vtd)
{
    __shared__ short As[128 * 64];
    __shared__ short Bs[128 * 64];
    const int z = blockIdx.z;
    const short* W = (z == 0) ? Wq : (z == 1) ? Wk : Wv;
    const float* bias = (z == 0) ? bq : (z == 1) ? (const float*)nullptr : bv;
    const float scale = (z == 2) ? 1.0f : 0.35355339059327373f;

    const int tid = threadIdx.x;
    const int w = tid >> 6, l = tid & 63;
    const int lg = l >> 4, lc = l & 15;
    const int wr = w >> 1, wc = w & 1;
    const int bm = blockIdx.x, bn = blockIdx.y;
    const int K = ND;

    const f32x4 zf = {0.f, 0.f, 0.f, 0.f};
    f32x4 acc[4][4];
#pragma unroll
    for (int a = 0; a < 4; ++a)
#pragma unroll
        for (int b2 = 0; b2 < 4; ++b2) acc[a][b2] = zf;

    for (int t = 0; t < 16; ++t) {
        const int k0 = t * 64;
        __syncthreads();
#pragma unroll
        for (int i = 0; i < 4; ++i) {
            int lin = i * 256 + tid;
            int row = lin >> 3, cp = lin & 7;
            int c = cp ^ (row & 7);
            GLOAD_LDS16(X + (size_t)(bm * 128 + row) * K + k0 + c * 8, As + lin * 8);
            GLOAD_LDS16(W + (size_t)(bn * 128 + row) * K + k0 + c * 8, Bs + lin * 8);
        }
        __syncthreads();

        short8 af[4][2], bfr[4][2];
#pragma unroll
        for (int mb = 0; mb < 4; ++mb) {
            int r = wr * 64 + mb * 16 + lc;
#pragma unroll
            for (int ks = 0; ks < 2; ++ks) {
                int c = (ks * 4 + lg) ^ (r & 7);
                af[mb][ks] = *(const short8*)(As + r * 64 + c * 8);
            }
        }
#pragma unroll
        for (int nb = 0; nb < 4; ++nb) {
            int r = wc * 64 + nb * 16 + lc;
#pragma unroll
            for (int ks = 0; ks < 2; ++ks) {
                int c = (ks * 4 + lg) ^ (r & 7);
                bfr[nb][ks] = *(const short8*)(Bs + r * 64 + c * 8);
            }
        }
#pragma unroll
        for (int mb = 0; mb < 4; ++mb)
#pragma unroll
            for (int nb = 0; nb < 4; ++nb)
#pragma unroll
                for (int ks = 0; ks < 2; ++ks)
                    acc[mb][nb] = mfma16(af[mb][ks], bfr[nb][ks], acc[mb][nb]);
    }

#pragma unroll
    for (int mb = 0; mb < 4; ++mb) {
        int m0 = bm * 128 + wr * 64 + mb * 16 + lg * 4;
        int b = m0 >> 10, s0 = m0 & 1023;
#pragma unroll
        for (int nb = 0; nb < 4; ++nb) {
            int n = bn * 128 + wc * 64 + nb * 16 + lc;
            int h = (n >> 6) & 15, d = n & 63;
            float bv_ = bias ? bias[n] : 0.f;
            if (z == 2) {
                // transposed V: [B,H,DH,S]; 4 consecutive s per lane -> 8B store
                s16x4 pk;
#pragma unroll
                for (int r = 0; r < 4; ++r) pk[r] = (short)f2bf(acc[mb][nb][r] + bv_);
                *(s16x4*)(vtd + (((size_t)(b * NH + h) * NDH + d) * NS + s0)) = pk;
            } else {
                short* dst = (z == 0) ? qd : kd;
#pragma unroll
                for (int r = 0; r < 4; ++r) {
                    float v = (acc[mb][nb][r] + bv_) * scale;
                    ((unsigned short*)dst)[(((size_t)(b * NH + h) * NS) + s0 + r) * NDH + d] =
                        f2bf(v);
                }
            }
        }
    }
}

// ---------------------------------------------------------------- O-projection GEMM
static __device__ __forceinline__ void stage_ab(
    const short* __restrict__ X, const short* __restrict__ W,
    int bm, int bn, int t, int tid, short* Asb, short* Bsb)
{
    const int k0 = t * 64;
#pragma unroll
    for (int i = 0; i < 4; ++i) {
        int lin = i * 256 + tid;
        int row = lin >> 3, cp = lin & 7;
        int c = cp ^ (row & 7);
        GLOAD_LDS16(X + (size_t)(bm * 128 + row) * ND + k0 + c * 8, Asb + lin * 8);
        GLOAD_LDS16(W + (size_t)(bn * 128 + row) * ND + k0 + c * 8, Bsb + lin * 8);
    }
}

static __device__ __forceinline__ void kstep128(
    const short* Asb, const short* Bsb, int wr, int wc, int lg, int lc,
    f32x4 acc[4][4])
{
    short8 af[4][2], bfr[4][2];
#pragma unroll
    for (int mb = 0; mb < 4; ++mb) {
        int r = wr * 64 + mb * 16 + lc;
#pragma unroll
        for (int ks = 0; ks < 2; ++ks) {
            int c = (ks * 4 + lg) ^ (r & 7);
            af[mb][ks] = *(const short8*)(Asb + r * 64 + c * 8);
        }
    }
#pragma unroll
    for (int nb = 0; nb < 4; ++nb) {
        int r = wc * 64 + nb * 16 + lc;
#pragma unroll
        for (int ks = 0; ks < 2; ++ks) {
            int c = (ks * 4 + lg) ^ (r & 7);
            bfr[nb][ks] = *(const short8*)(Bsb + r * 64 + c * 8);
        }
    }
#pragma unroll
    for (int mb = 0; mb < 4; ++mb)
#pragma unroll
        for (int nb = 0; nb < 4; ++nb)
#pragma unroll
            for (int ks = 0; ks < 2; ++ks)
                acc[mb][nb] = mfma16(af[mb][ks], bfr[nb][ks], acc[mb][nb]);
}

__global__ __launch_bounds__(256) void gemm_out(
    const short* __restrict__ X, const short* __restrict__ W,
    const float* __restrict__ bias, float* __restrict__ outp)
{
    __shared__ short As0[128 * 64], As1[128 * 64];
    __shared__ short Bs0[128 * 64], Bs1[128 * 64];
    const int tid = threadIdx.x;
    const int w = tid >> 6, l = tid & 63;
    const int lg = l >> 4, lc = l & 15;
    const int wr = w >> 1, wc = w & 1;
    const int bm = blockIdx.x, bn = blockIdx.y;

    const f32x4 zf = {0.f, 0.f, 0.f, 0.f};
    f32x4 acc[4][4];
#pragma unroll
    for (int a = 0; a < 4; ++a)
#pragma unroll
        for (int b2 = 0; b2 < 4; ++b2) acc[a][b2] = zf;

    stage_ab(X, W, bm, bn, 0, tid, As0, Bs0);
    __syncthreads();
    for (int t = 0; t < 16; t += 2) {
        if (t + 1 < 16) stage_ab(X, W, bm, bn, t + 1, tid, As1, Bs1);
        kstep128(As0, Bs0, wr, wc, lg, lc, acc);
        __syncthreads();
        if (t + 2 < 16) stage_ab(X, W, bm, bn, t + 2, tid, As0, Bs0);
        kstep128(As1, Bs1, wr, wc, lg, lc, acc);
        __syncthreads();
    }

#pragma unroll
    for (int mb = 0; mb < 4; ++mb) {
        int m0 = bm * 128 + wr * 64 + mb * 16 + lg * 4;
#pragma unroll
        for (int nb = 0; nb < 4; ++nb) {
            int n = bn * 128 + wc * 64 + nb * 16 + lc;
            float bv_ = bias[n];
#pragma unroll
            for (int r = 0; r < 4; ++r)
                outp[(size_t)(m0 + r) * ND + n] = acc[mb][nb][r] + bv_;
        }
    }
}

// ---------------------------------------------------------------- fused MFMA attention
// Barrier-free: K/V B-frags are contiguous 16B runs in global memory (L2-hot,
// 16x reuse per head) -> no LDS staging, no global_load_lds, no __syncthreads.
// Only LDS use is the wave-private P roundtrip (8.7 KB). 16 waves/CU via
// __launch_bounds__(256,4); latency hidden by TLP+ILP.
__global__ __launch_bounds__(256, 4) void attn_mfma(
    const short* __restrict__ qb, const short* __restrict__ kb,
    const short* __restrict__ vt, const int* __restrict__ mask,
    float* __restrict__ qk_out, unsigned short* __restrict__ wv_out)
{
    __shared__ short Ps[4][16 * 68];
    const int qt = blockIdx.x, bh = blockIdx.y;
    const int b = bh >> 4, h = bh & 15;
    const int q0 = qt * 64;
    const int tid = threadIdx.x;
    const int w = tid >> 6, l = tid & 63;
    const int lg = l >> 4, lc = l & 15;

    short8 aq0, aq1;
    {
        const short* qrow = qb + ((size_t)(bh * NS + q0 + w * 16 + lc)) * NDH;
        aq0 = *(const short8*)(qrow + lg * 8);
        aq1 = *(const short8*)(qrow + 32 + lg * 8);
    }

    const f32x4 zf = {0.f, 0.f, 0.f, 0.f};
    f32x4 o[4];
#pragma unroll
    for (int db = 0; db < 4; ++db) o[db] = zf;
    float mr = -INFINITY, lr = 0.f;      // stats for q = q0 + w*16 + lc (lane-local)

    const size_t qrowbase = (size_t)(bh * NS + q0 + w * 16 + lc) * NS;
    const short* kbase = kb + (size_t)bh * NS * NDH;
    const short* vbase = vt + (size_t)bh * NDH * NS;
    const int* mbase = mask + b * NS;
    short* psw = &Ps[w][0];

    for (int t = 0; t < 16; ++t) {
        // S^T = K Q^T : per lane q = lc, k = jb*16 + lg*4 + r; K-frags direct
        f32x4 s[4];
#pragma unroll
        for (int jb = 0; jb < 4; ++jb) {
            const short* kr = kbase + (size_t)(t * 64 + jb * 16 + lc) * NDH + lg * 8;
            s[jb] = mfma16(*(const short8*)kr, aq0, zf);
            s[jb] = mfma16(*(const short8*)(kr + 32), aq1, s[jb]);
        }

        // mask (cached int4 broadcast) + sentinel store; in-place mask for softmax
#pragma unroll
        for (int jb = 0; jb < 4; ++jb) {
            int4 mi = *(const int4*)(mbase + t * 64 + jb * 16 + lg * 4);
            f32x4 sv;
            sv[0] = mi.x ? s[jb][0] : SENT;
            sv[1] = mi.y ? s[jb][1] : SENT;
            sv[2] = mi.z ? s[jb][2] : SENT;
            sv[3] = mi.w ? s[jb][3] : SENT;
            __builtin_nontemporal_store(
                sv, (f32x4*)(qk_out + qrowbase + t * 64 + jb * 16 + lg * 4));
            s[jb][0] = mi.x ? s[jb][0] : -INFINITY;
            s[jb][1] = mi.y ? s[jb][1] : -INFINITY;
            s[jb][2] = mi.z ? s[jb][2] : -INFINITY;
            s[jb][3] = mi.w ? s[jb][3] : -INFINITY;
        }

        // online softmax, scalar per lane (q = lc)
        float pm = -INFINITY;
#pragma unroll
        for (int jb = 0; jb < 4; ++jb)
            pm = fmaxf(pm, fmaxf(fmaxf(s[jb][0], s[jb][1]),
                                 fmaxf(s[jb][2], s[jb][3])));
        pm = fmaxf(pm, __shfl_xor(pm, 16));
        pm = fmaxf(pm, __shfl_xor(pm, 32));

        float nm = fmaxf(mr, pm);
        float f = (nm == -INFINITY) ? 1.f : __expf(mr - nm);
        float nms = (nm == -INFINITY) ? 0.f : nm;
        mr = nm;

        float p[4][4], ps_ = 0.f;
#pragma unroll
        for (int jb = 0; jb < 4; ++jb)
#pragma unroll
            for (int r = 0; r < 4; ++r) {
                float e = __expf(s[jb][r] - nms);   // masked -> exp(-inf)=0
                p[jb][r] = e;
                ps_ += e;
            }
        ps_ += __shfl_xor(ps_, 16);
        ps_ += __shfl_xor(ps_, 32);
        lr = lr * f + ps_;

        // rescale O: o rows are q = lg*4 + r -> broadcast f from lane lc=q
        f32x4 fv;
#pragma unroll
        for (int r = 0; r < 4; ++r) fv[r] = __shfl(f, lg * 4 + r, 16);
#pragma unroll
        for (int db = 0; db < 4; ++db) o[db] *= fv;

        // P^T fragment -> wave-private LDS (8B writes), reread as A-frag
#pragma unroll
        for (int jb = 0; jb < 4; ++jb) {
            s16x4 pk;
#pragma unroll
            for (int r = 0; r < 4; ++r) pk[r] = (short)f2bf(p[jb][r]);
            *(s16x4*)(psw + lc * 68 + jb * 16 + lg * 4) = pk;
        }
        short8 pa0 = *(const short8*)(psw + lc * 68 + lg * 8);
        short8 pa1 = *(const short8*)(psw + lc * 68 + 32 + lg * 8);

        // O += P @ V; V^T B-frags direct from global (row d = db*16+lc)
#pragma unroll
        for (int db = 0; db < 4; ++db) {
            const short* vr = vbase + (size_t)(db * 16 + lc) * NS + t * 64 + lg * 8;
            o[db] = mfma16(pa0, *(const short8*)vr, o[db]);
            o[db] = mfma16(pa1, *(const short8*)(vr + 32), o[db]);
        }
    }

    float inv = (lr > 0.f) ? 1.f / lr : 0.f;
    f32x4 invv;
#pragma unroll
    for (int r = 0; r < 4; ++r) invv[r] = __shfl(inv, lg * 4 + r, 16);
#pragma unroll
    for (int db = 0; db < 4; ++db)
#pragma unroll
        for (int r = 0; r < 4; ++r) {
            float v = o[db][r] * invv[r];
            wv_out[(((size_t)(b * NS + q0 + w * 16 + lg * 4 + r)) * NH + h) * NDH + db * 16 + lc] =
                f2bf(v);
        }
}

// ---------------------------------------------------------------- launch
extern "C" void kernel_launch(void* const* d_in, const int* in_sizes, int n_in,
                              void* d_out, int out_size, void* d_ws, size_t ws_size,
                              hipStream_t stream) {
    const float* x    = (const float*)d_in[0];
    const int*   mask = (const int*)d_in[1];
    const float* Wq   = (const float*)d_in[2];
    const float* bq   = (const float*)d_in[3];
    const float* Wk   = (const float*)d_in[4];
    const float* Wv   = (const float*)d_in[5];
    const float* bv   = (const float*)d_in[6];
    const float* Wo   = (const float*)d_in[7];
    const float* bo   = (const float*)d_in[8];

    float* out    = (float*)d_out;                      // [B,S,D] f32
    float* qk_out = out + (size_t)NB * NS * ND;         // [B,H,S,S] f32

    const size_t MI = 1u << 20;
    short* xb  = (short*)d_ws;          // 4 MI
    short* wqb = xb  + 4 * MI;          // 1 MI
    short* wkb = wqb + MI;
    short* wvb = wkb + MI;
    short* wob = wvb + MI;
    short* qbf = wob + MI;              // 4 MI  [B,H,S,DH]
    short* kbf = qbf + 4 * MI;          // 4 MI  [B,H,S,DH]
    short* vtb = kbf + 4 * MI;          // 4 MI  [B,H,DH,S]
    short* wvo = vtb + 4 * MI;          // 4 MI  [B,S,H,DH]

    cast_to_bf16<<<8192, 256, 0, stream>>>(x, Wq, Wk, Wv, Wo, xb, wqb, wkb, wvb, wob);

    dim3 blk(256);
    dim3 qgrid(32, 8, 3);
    gemm_qkv<<<qgrid, blk, 0, stream>>>(xb, wqb, wkb, wvb, bq, bv, qbf, kbf, vtb);

    dim3 agrid(16, 64);
    attn_mfma<<<agrid, blk, 0, stream>>>(qbf, kbf, vtb, mask, qk_out, (unsigned short*)wvo);

    dim3 ogrid(32, 8);
    gemm_out<<<ogrid, blk, 0, stream>>>(wvo, wob, bo, out);
}